// Round 11
// baseline (464.846 us; speedup 1.0000x reference)
//
#include <hip/hip_runtime.h>
#include <hip/hip_bf16.h>
#include <cmath>

#define HID 128
#define TM 64           // tile rows per block
#define MAXK 8          // max tiles a segment can span (seg len <= ~512)
#define PIECE_F 132     // floats per piece: [m, d, pad, pad, p[128]]

typedef __attribute__((ext_vector_type(8))) short bf16x8;
typedef __attribute__((ext_vector_type(4))) float f32x4;
typedef __attribute__((ext_vector_type(2))) float f32x2;

__device__ __forceinline__ float exp2_fast(float x) {
    float r;
    asm("v_exp_f32 %0, %1" : "=v"(r) : "v"(x));
    return r;
}

// tanh(x) = 1 - 2/(2^(2*log2e*x) + 1)
__device__ __forceinline__ float fast_tanh(float x) {
    float e = exp2_fast(x * 2.885390082f);
    return 1.0f - 2.0f * __builtin_amdgcn_rcpf(e + 1.0f);
}

// Pack 8 floats -> 8 bf16 RNE via hardware cvt (compiler pairs into
// v_cvt_pk_bf16_f32; ~4 ops vs ~27 for bit-twiddle RNE).
__device__ __forceinline__ bf16x8 pack8(const float* f) {
    union { short h8[8]; bf16x8 v; } u;
    #pragma unroll
    for (int q = 0; q < 8; ++q)
        u.h8[q] = (short)__bfloat16_as_ushort(__float2bfloat16(f[q]));
    return u.v;
}

// ---------------------------------------------------------------------------
// Prep: W -> bf16 RNE in exact 16x16x32 A-fragment order:
// id = (ks*8 + jt)*64 + lane; holds W[jt*16 + (lane&15)][ks*32 + (lane>>4)*8 + q]
// ---------------------------------------------------------------------------
__global__ __launch_bounds__(256) void prep_w_frag(
    const float* __restrict__ W, short* __restrict__ whi)
{
    int id = blockIdx.x * 256 + threadIdx.x;    // 0..2047
    int l  = id & 63;
    int jt = (id >> 6) & 7;
    int ks = id >> 9;                           // 0..3
    int j  = jt * 16 + (l & 15);
    int k0 = ks * 32 + ((l >> 4) << 3);
    const float* src = W + j * HID + k0;
    float a8[8];
    #pragma unroll
    for (int q = 0; q < 8; ++q) a8[q] = src[q];
    *(bf16x8*)(whi + (size_t)id * 8) = pack8(a8);
}

// ---------------------------------------------------------------------------
// Segment starts from sorted owners (int32/int64) + first-segment per TM-tile.
// ---------------------------------------------------------------------------
__global__ void seg_start_kernel(const int* __restrict__ ow,
                                 int* __restrict__ seg_start,
                                 int* __restrict__ fseg, int N, int S)
{
    const int is64 = (ow[(size_t)N - 1] == 0) ? 1 : 0;
    long i = (long)blockIdx.x * blockDim.x + threadIdx.x;
    if (i > N) return;
    int a = (i == 0) ? -1 : ow[is64 ? (size_t)(2 * (i - 1)) : (size_t)(i - 1)];
    int b = (i == N) ? S  : ow[is64 ? (size_t)(2 * i)       : (size_t)i];
    for (int s = a + 1; s <= b; ++s) seg_start[s] = (int)i;
    if (i < N && (i & (TM - 1)) == 0) fseg[i >> 6] = b;  // owner of row i
}

// ---------------------------------------------------------------------------
// INSTRUMENTATION BUILD: grid = 3*NT; blocks bIdx >= NT redo tiles with
// identical work but write a dummy pieces buffer, tripling dispatch time so
// the fused row outranks the harness's ~300us poison fills in rocprof top-5.
// Body = round-10 structure (176us best) + cvt-based pack8.
// X LDS layout (shorts): chunk c (8 bf16) of row r at r*128 + (c^(r&7))*8.
// ---------------------------------------------------------------------------
__global__ __launch_bounds__(256, 8) void fused_kernel(
    const float* __restrict__ X, const short* __restrict__ whi_g,
    const float* __restrict__ bproj, const float* __restrict__ wscore,
    const int* __restrict__ seg_start, const int* __restrict__ fseg,
    float* __restrict__ pieces, float* __restrict__ pieces2,
    int N, int S, int NT)
{
    __shared__ __align__(16) short X_lds[TM * HID];     // 16 KB bf16
    __shared__ float u_lds[TM];
    __shared__ float w_lds[TM];
    __shared__ float bw_lds[2 * HID];

    const int bIdx = blockIdx.x;
    const int dup  = (bIdx >= NT);
    const int T    = dup ? ((bIdx >= 2 * NT) ? bIdx - 2 * NT : bIdx - NT) : bIdx;
    float* pout    = dup ? pieces2 : pieces;

    const int tid  = threadIdx.x;
    const int rbase = T * TM;
    const int limit = (N - rbase < TM) ? (N - rbase) : TM;

    const int lane = tid & 63;
    const int wv   = tid >> 6;
    const int l15  = lane & 15;
    const int kq   = lane >> 4;       // 0..3

    const int sseg0 = fseg[T];        // issued early
    int svl = sseg0 + lane;
    int sv  = seg_start[(svl <= S) ? svl : S];

    // --- stage X: read 32B f32, cvt to bf16 RNE, write 16B chunk ---
    #pragma unroll
    for (int it = 0; it < 4; ++it) {
        int id = it * 256 + tid;          // 0..1023
        int r  = id >> 4;                 // 0..63
        int c  = id & 15;                 // 8-elem chunk
        int grow = rbase + r;
        if (grow >= N) grow = N - 1;
        float a8[8];
        *(f32x4*)(a8)     = *(const f32x4*)(X + (size_t)grow * HID + c * 8);
        *(f32x4*)(a8 + 4) = *(const f32x4*)(X + (size_t)grow * HID + c * 8 + 4);
        *(bf16x8*)(&X_lds[r * HID + ((c ^ (r & 7)) << 3)]) = pack8(a8);
    }
    if (tid < HID) {
        bw_lds[tid]       = bproj[tid];
        bw_lds[HID + tid] = wscore[tid];
    }
    __syncthreads();

    // ---- MFMA: v[j][i], wave owns rows i0..i0+15 ----
    const int i0 = wv * 16;
    const int r  = i0 + l15;
    f32x4 acc[8];
    #pragma unroll
    for (int jt = 0; jt < 8; ++jt)
        #pragma unroll
        for (int q = 0; q < 4; ++q) acc[jt][q] = 0.0f;

    #pragma unroll
    for (int ks = 0; ks < 4; ++ks) {
        int t = ks * 4 + kq;              // this lane's k-octet chunk
        bf16x8 xf = *(const bf16x8*)(&X_lds[r * HID + ((t ^ (r & 7)) << 3)]);
        #pragma unroll
        for (int jt = 0; jt < 8; ++jt) {
            bf16x8 wf = *(const bf16x8*)(
                whi_g + (size_t)(((ks * 8 + jt) * 64 + lane)) * 8);
            acc[jt] = __builtin_amdgcn_mfma_f32_16x16x32_bf16(wf, xf, acc[jt], 0, 0, 0);
        }
    }

    // ---- epilogue: u_i = sum_j w_j * tanh(v_ji + b_j) ----
    // D layout: col i = lane&15, row j = jt*16 + (lane>>4)*4 + reg
    float s = 0.0f;
    #pragma unroll
    for (int jt = 0; jt < 8; ++jt)
        #pragma unroll
        for (int reg = 0; reg < 4; ++reg) {
            int j = jt * 16 + kq * 4 + reg;
            s = fmaf(fast_tanh(acc[jt][reg] + bw_lds[j]), bw_lds[HID + j], s);
        }
    s += __shfl_xor(s, 16, 64);
    s += __shfl_xor(s, 32, 64);
    if (lane < 16) u_lds[i0 + lane] = s;   // b_score cancels in softmax
    __syncthreads();

    // ---- phase 2: one wave per piece (piece <= 64 rows) ----
    // lane owns cols {2*lane, 2*lane+1}: chunk cc = lane>>2, short off (lane&3)*2
    const int cc  = lane >> 2;
    const int co  = (lane & 3) << 1;
    for (int i = wv; ; i += 4) {
        int st, en;
        if (i < 63) {
            st = __shfl(sv, i, 64);
            en = __shfl(sv, i + 1, 64);
        } else {
            int s0 = sseg0 + i;
            st = seg_start[(s0     <= S) ? s0     : S];
            en = seg_start[(s0 + 1 <= S) ? s0 + 1 : S];
        }
        if (st >= rbase + limit) break;    // starts monotone -> done
        if (en <= st) continue;            // empty segment
        int a  = st - rbase; if (a < 0) a = 0;
        int bb = en - rbase; if (bb > limit) bb = limit;
        if (a >= bb) continue;

        float u0 = (a + lane < bb) ? u_lds[a + lane] : -INFINITY;
        float m = u0;
        #pragma unroll
        for (int o = 32; o > 0; o >>= 1) m = fmaxf(m, __shfl_xor(m, o, 64));
        float e0 = (a + lane < bb) ? exp2_fast((u0 - m) * 1.442695041f) : 0.0f;
        float d = e0;
        #pragma unroll
        for (int o = 32; o > 0; o >>= 1) d += __shfl_xor(d, o, 64);
        if (a + lane < bb) w_lds[a + lane] = e0;

        // p[c] = sum_r e_r * x[r][c]; unmasked quad loop + scalar tail
        f32x2 p = {0.0f, 0.0f};
        int rr = a;
        for (; rr + 4 <= bb; rr += 4) {
            #pragma unroll
            for (int q = 0; q < 4; ++q) {
                int rc = rr + q;
                float wq = w_lds[rc];
                unsigned pr = *(const unsigned*)(
                    &X_lds[rc * HID + ((cc ^ (rc & 7)) << 3) + co]);
                float x0 = __builtin_bit_cast(float, pr << 16);
                float x1 = __builtin_bit_cast(float, pr & 0xFFFF0000u);
                p.x = fmaf(wq, x0, p.x);
                p.y = fmaf(wq, x1, p.y);
            }
        }
        for (; rr < bb; ++rr) {
            float wq = w_lds[rr];
            unsigned pr = *(const unsigned*)(
                &X_lds[rr * HID + ((cc ^ (rr & 7)) << 3) + co]);
            float x0 = __builtin_bit_cast(float, pr << 16);
            float x1 = __builtin_bit_cast(float, pr & 0xFFFF0000u);
            p.x = fmaf(wq, x0, p.x);
            p.y = fmaf(wq, x1, p.y);
        }

        int sseg = sseg0 + i;
        int slot = (T - (st >> 6)) & (MAXK - 1);
        float* dst = pout + ((size_t)sseg * MAXK + slot) * PIECE_F;
        if (lane == 0) { dst[0] = m; dst[1] = d; }
        *(f32x2*)(dst + 4 + 2 * lane) = p;
    }
}

// ---------------------------------------------------------------------------
// Fixup: merge pieces per segment -> z[s][:].
// ---------------------------------------------------------------------------
__global__ __launch_bounds__(64) void fixup_kernel(
    const float* __restrict__ pieces, const int* __restrict__ seg_start,
    float* __restrict__ z)
{
    const int s = blockIdx.x;
    const int lane = threadIdx.x;
    const int start = seg_start[s];
    const int end   = seg_start[s + 1];

    if (start >= end) {
        f32x2 zo = {0.0f, 0.0f};
        *(f32x2*)(z + (size_t)s * HID + lane * 2) = zo;
        return;
    }
    int K = ((end - 1) >> 6) - (start >> 6) + 1;
    if (K > MAXK) K = MAXK;

    const float* base0 = pieces + (size_t)s * MAXK * PIECE_F;
    float M = -INFINITY;
    for (int k = 0; k < K; ++k) M = fmaxf(M, base0[k * PIECE_F]);

    float D = 0.0f;
    f32x2 zz = {0.0f, 0.0f};
    for (int k = 0; k < K; ++k) {
        const float* b = base0 + k * PIECE_F;
        float sc = __expf(b[0] - M);
        D = fmaf(b[1], sc, D);
        f32x2 pv = *(const f32x2*)(b + 4 + lane * 2);
        zz.x = fmaf(sc, pv.x, zz.x);
        zz.y = fmaf(sc, pv.y, zz.y);
    }
    float inv = 1.0f / D;
    f32x2 zo = {zz.x * inv, zz.y * inv};
    *(f32x2*)(z + (size_t)s * HID + lane * 2) = zo;
}

// ---------------------------------------------------------------------------
extern "C" void kernel_launch(void* const* d_in, const int* in_sizes, int n_in,
                              void* d_out, int out_size, void* d_ws, size_t ws_size,
                              hipStream_t stream)
{
    const float* X   = (const float*)d_in[0];
    const int*   ow  = (const int*)  d_in[1];
    const float* W   = (const float*)d_in[2];
    const float* bp  = (const float*)d_in[3];
    const float* wsc = (const float*)d_in[4];

    const int N  = in_sizes[0] / HID;
    const int S  = out_size / HID;
    const int NT = (N + TM - 1) / TM;

    const size_t piece_bytes = (size_t)S * MAXK * PIECE_F * 4;

    char* ws = (char*)d_ws;
    size_t off_seg = 0;
    size_t off_fs  = (((size_t)(S + 1) * 4) + 255) & ~(size_t)255;
    size_t off_w   = (off_fs + (size_t)NT * 4 + 255) & ~(size_t)255;
    size_t off_pc  = (off_w + (size_t)HID * HID * 2 + 255) & ~(size_t)255;
    size_t off_pc2 = (off_pc + piece_bytes + 255) & ~(size_t)255;

    int*   seg     = (int*)  (ws + off_seg);
    int*   fsg     = (int*)  (ws + off_fs);
    short* whi     = (short*)(ws + off_w);
    float* pieces  = (float*)(ws + off_pc);
    float* pieces2 = (float*)(ws + off_pc2);
    float* z       = (float*)d_out;

    const int blocksB = ((N + 1) + 255) / 256;
    seg_start_kernel<<<blocksB, 256, 0, stream>>>(ow, seg, fsg, N, S);

    prep_w_frag<<<8, 256, 0, stream>>>(W, whi);

    fused_kernel<<<3 * NT, 256, 0, stream>>>(X, whi, bp, wsc, seg, fsg,
                                             pieces, pieces2, N, S, NT);

    fixup_kernel<<<S, 64, 0, stream>>>(pieces, seg, z);
}

// Round 12
// 125.852 us; speedup vs baseline: 3.6936x; 3.6936x over previous
//
#include <hip/hip_runtime.h>
#include <hip/hip_bf16.h>
#include <cmath>

#define HID 128
#define TM 64           // tile rows per block
#define MAXK 8          // max tiles a segment can span (seg len <= ~512)
#define PIECE_F 132     // floats per piece: [m, d, pad, pad, p[128]]
#define XP 132          // shorts per LDS X row: 264B pitch -> <=2-way banks

typedef __attribute__((ext_vector_type(8))) short bf16x8;
typedef __attribute__((ext_vector_type(16))) float f32x16;
typedef __attribute__((ext_vector_type(4))) float f32x4;
typedef __attribute__((ext_vector_type(2))) float f32x2;

__device__ __forceinline__ float exp2_fast(float x) {
    float r;
    asm("v_exp_f32 %0, %1" : "=v"(r) : "v"(x));
    return r;
}

// tanh(x) = 1 - 2/(2^(2*log2e*x) + 1)
__device__ __forceinline__ float fast_tanh(float x) {
    float e = exp2_fast(x * 2.885390082f);
    return 1.0f - 2.0f * __builtin_amdgcn_rcpf(e + 1.0f);
}

// Pack 8 floats -> 8 bf16 RNE via hardware cvt (pairs into v_cvt_pk_bf16_f32).
__device__ __forceinline__ bf16x8 pack8(const float* f) {
    union { short h8[8]; bf16x8 v; } u;
    #pragma unroll
    for (int q = 0; q < 8; ++q)
        u.h8[q] = (short)__bfloat16_as_ushort(__float2bfloat16(f[q]));
    return u.v;
}

// ---------------------------------------------------------------------------
// Prep: W -> bf16 RNE in per-wave register-fragment order for 32x32x16:
// id = (wv*8 + kc)*64 + lane holds W[wv*32 + (lane&31)][kc*16 + (lane>>5)*8 + q]
// (layout verified in round 8)
// ---------------------------------------------------------------------------
__global__ __launch_bounds__(256) void prep_w_frag(
    const float* __restrict__ W, short* __restrict__ whi)
{
    int id = blockIdx.x * 256 + threadIdx.x;    // 0..2047
    int l  = id & 63;
    int kc = (id >> 6) & 7;
    int wv = id >> 9;                           // 0..3
    int j  = wv * 32 + (l & 31);
    int k0 = kc * 16 + ((l >> 5) << 3);
    const float* src = W + j * HID + k0;
    float a8[8];
    #pragma unroll
    for (int q = 0; q < 8; ++q) a8[q] = src[q];
    *(bf16x8*)(whi + (size_t)id * 8) = pack8(a8);
}

// ---------------------------------------------------------------------------
// Segment starts from sorted owners (int32/int64) + first-segment per TM-tile.
// ---------------------------------------------------------------------------
__global__ void seg_start_kernel(const int* __restrict__ ow,
                                 int* __restrict__ seg_start,
                                 int* __restrict__ fseg, int N, int S)
{
    const int is64 = (ow[(size_t)N - 1] == 0) ? 1 : 0;
    long i = (long)blockIdx.x * blockDim.x + threadIdx.x;
    if (i > N) return;
    int a = (i == 0) ? -1 : ow[is64 ? (size_t)(2 * (i - 1)) : (size_t)(i - 1)];
    int b = (i == N) ? S  : ow[is64 ? (size_t)(2 * i)       : (size_t)i];
    for (int s = a + 1; s <= b; ++s) seg_start[s] = (int)i;
    if (i < N && (i & (TM - 1)) == 0) fseg[i >> 6] = b;  // owner of row i
}

// ---------------------------------------------------------------------------
// Fused, 64-row tile, j-split waves: wave wv owns output cols
// [wv*32, wv*32+32) for ALL 64 rows; its W slice = 32 VGPRs loaded ONCE.
// X in LDS as bf16, pitch XP=132 shorts (<=2-way banks everywhere).
// ---------------------------------------------------------------------------
__global__ __launch_bounds__(256, 4) void fused_kernel(
    const float* __restrict__ X, const short* __restrict__ whi_g,
    const float* __restrict__ bproj, const float* __restrict__ wscore,
    const int* __restrict__ seg_start, const int* __restrict__ fseg,
    float* __restrict__ pieces, int N, int S)
{
    __shared__ __align__(16) short X_lds[TM * XP];   // ~16.9 KB
    __shared__ float u_part[4][TM];
    __shared__ float w_lds[TM];
    __shared__ float bw_lds[2 * HID];                // packed {b[j], w[j]}

    const int tid  = threadIdx.x;
    const int bIdx = blockIdx.x;
    const int rbase = bIdx * TM;
    const int limit = (N - rbase < TM) ? (N - rbase) : TM;

    const int lane = tid & 63;
    const int wv   = tid >> 6;
    const int l31  = lane & 31;
    const int hig  = lane >> 5;

    // --- W slice for this wave: 8 frags = 32 VGPRs, loaded once ---
    bf16x8 wf[8];
    #pragma unroll
    for (int kc = 0; kc < 8; ++kc)
        wf[kc] = *(const bf16x8*)(whi_g + (size_t)((wv * 8 + kc) * 64 + lane) * 8);

    const int sseg0 = fseg[bIdx];
    int svl = sseg0 + lane;
    int sv  = seg_start[(svl <= S) ? svl : S];

    // --- stage X: read 32B f32, cvt bf16, write 16B chunk (pitch XP) ---
    #pragma unroll
    for (int it = 0; it < 4; ++it) {
        int id = it * 256 + tid;          // 0..1023
        int r  = id >> 4;                 // 0..63
        int c  = id & 15;                 // 8-elem chunk
        int grow = rbase + r;
        if (grow >= N) grow = N - 1;
        float a8[8];
        *(f32x4*)(a8)     = *(const f32x4*)(X + (size_t)grow * HID + c * 8);
        *(f32x4*)(a8 + 4) = *(const f32x4*)(X + (size_t)grow * HID + c * 8 + 4);
        *(bf16x8*)(&X_lds[r * XP + c * 8]) = pack8(a8);
    }
    if (tid < HID) {
        bw_lds[2 * tid]     = bproj[tid];
        bw_lds[2 * tid + 1] = wscore[tid];
    }
    __syncthreads();

    // ---- MFMA 32x32x16: acc0 covers i=l31, acc1 covers i=32+l31 ----
    f32x16 acc0, acc1;
    #pragma unroll
    for (int g = 0; g < 16; ++g) { acc0[g] = 0.0f; acc1[g] = 0.0f; }

    #pragma unroll
    for (int kc = 0; kc < 8; ++kc) {
        int c = kc * 2 + hig;             // chunk holding this lane's k-octet
        bf16x8 x0 = *(const bf16x8*)(&X_lds[l31 * XP + c * 8]);
        bf16x8 x1 = *(const bf16x8*)(&X_lds[(32 + l31) * XP + c * 8]);
        acc0 = __builtin_amdgcn_mfma_f32_32x32x16_bf16(wf[kc], x0, acc0, 0, 0, 0);
        acc1 = __builtin_amdgcn_mfma_f32_32x32x16_bf16(wf[kc], x1, acc1, 0, 0, 0);
    }

    // ---- epilogue: partial u over this wave's 32 j's ----
    // D layout (32x32): col i = lane&31; row j = (reg&3)+8*(reg>>2)+4*hig
    float s0 = 0.0f, s1 = 0.0f;
    #pragma unroll
    for (int reg = 0; reg < 16; ++reg) {
        int j = wv * 32 + (reg & 3) + ((reg >> 2) << 3) + (hig << 2);
        f32x2 bw = *(const f32x2*)(&bw_lds[2 * j]);
        s0 = fmaf(fast_tanh(acc0[reg] + bw.x), bw.y, s0);
        s1 = fmaf(fast_tanh(acc1[reg] + bw.x), bw.y, s1);
    }
    s0 += __shfl_xor(s0, 32, 64);
    s1 += __shfl_xor(s1, 32, 64);
    if (hig == 0) {
        u_part[wv][l31]      = s0;
        u_part[wv][32 + l31] = s1;
    }
    __syncthreads();

    // ---- phase 2: one wave per piece (piece <= 64 rows) ----
    for (int i = wv; ; i += 4) {
        int st, en;
        if (i < 63) {
            st = __shfl(sv, i, 64);
            en = __shfl(sv, i + 1, 64);
        } else {
            int s0i = sseg0 + i;
            st = seg_start[(s0i     <= S) ? s0i     : S];
            en = seg_start[(s0i + 1 <= S) ? s0i + 1 : S];
        }
        if (st >= rbase + limit) break;    // starts monotone -> done
        if (en <= st) continue;            // empty segment
        int a  = st - rbase; if (a < 0) a = 0;
        int bb = en - rbase; if (bb > limit) bb = limit;
        if (a >= bb) continue;

        float uv = -INFINITY;
        if (a + lane < bb)
            uv = u_part[0][a + lane] + u_part[1][a + lane]
               + u_part[2][a + lane] + u_part[3][a + lane];
        float m = uv;
        #pragma unroll
        for (int o = 32; o > 0; o >>= 1) m = fmaxf(m, __shfl_xor(m, o, 64));
        float e0 = (a + lane < bb) ? exp2_fast((uv - m) * 1.442695041f) : 0.0f;
        float d = e0;
        #pragma unroll
        for (int o = 32; o > 0; o >>= 1) d += __shfl_xor(d, o, 64);
        if (a + lane < bb) w_lds[a + lane] = e0;

        // p[c] = sum_r e_r * x[r][c]; lane owns cols {2*lane, 2*lane+1}
        f32x2 p = {0.0f, 0.0f};
        int rr = a;
        for (; rr + 4 <= bb; rr += 4) {
            #pragma unroll
            for (int q = 0; q < 4; ++q) {
                int rc = rr + q;
                float wq = w_lds[rc];
                unsigned pr = *(const unsigned*)(&X_lds[rc * XP + 2 * lane]);
                float x0 = __builtin_bit_cast(float, pr << 16);
                float x1 = __builtin_bit_cast(float, pr & 0xFFFF0000u);
                p.x = fmaf(wq, x0, p.x);
                p.y = fmaf(wq, x1, p.y);
            }
        }
        for (; rr < bb; ++rr) {
            float wq = w_lds[rr];
            unsigned pr = *(const unsigned*)(&X_lds[rr * XP + 2 * lane]);
            float x0 = __builtin_bit_cast(float, pr << 16);
            float x1 = __builtin_bit_cast(float, pr & 0xFFFF0000u);
            p.x = fmaf(wq, x0, p.x);
            p.y = fmaf(wq, x1, p.y);
        }

        int sseg = sseg0 + i;
        int slot = (bIdx - (st >> 6)) & (MAXK - 1);
        float* dst = pieces + ((size_t)sseg * MAXK + slot) * PIECE_F;
        if (lane == 0) { dst[0] = m; dst[1] = d; }
        *(f32x2*)(dst + 4 + 2 * lane) = p;
    }
}

// ---------------------------------------------------------------------------
// Fixup: merge pieces per segment -> z[s][:].
// ---------------------------------------------------------------------------
__global__ __launch_bounds__(64) void fixup_kernel(
    const float* __restrict__ pieces, const int* __restrict__ seg_start,
    float* __restrict__ z)
{
    const int s = blockIdx.x;
    const int lane = threadIdx.x;
    const int start = seg_start[s];
    const int end   = seg_start[s + 1];

    if (start >= end) {
        f32x2 zo = {0.0f, 0.0f};
        *(f32x2*)(z + (size_t)s * HID + lane * 2) = zo;
        return;
    }
    int K = ((end - 1) >> 6) - (start >> 6) + 1;
    if (K > MAXK) K = MAXK;

    const float* base0 = pieces + (size_t)s * MAXK * PIECE_F;
    float M = -INFINITY;
    for (int k = 0; k < K; ++k) M = fmaxf(M, base0[k * PIECE_F]);

    float D = 0.0f;
    f32x2 zz = {0.0f, 0.0f};
    for (int k = 0; k < K; ++k) {
        const float* b = base0 + k * PIECE_F;
        float sc = __expf(b[0] - M);
        D = fmaf(b[1], sc, D);
        f32x2 pv = *(const f32x2*)(b + 4 + lane * 2);
        zz.x = fmaf(sc, pv.x, zz.x);
        zz.y = fmaf(sc, pv.y, zz.y);
    }
    float inv = 1.0f / D;
    f32x2 zo = {zz.x * inv, zz.y * inv};
    *(f32x2*)(z + (size_t)s * HID + lane * 2) = zo;
}

// ---------------------------------------------------------------------------
extern "C" void kernel_launch(void* const* d_in, const int* in_sizes, int n_in,
                              void* d_out, int out_size, void* d_ws, size_t ws_size,
                              hipStream_t stream)
{
    const float* X   = (const float*)d_in[0];
    const int*   ow  = (const int*)  d_in[1];
    const float* W   = (const float*)d_in[2];
    const float* bp  = (const float*)d_in[3];
    const float* wsc = (const float*)d_in[4];

    const int N  = in_sizes[0] / HID;
    const int S  = out_size / HID;
    const int NT = (N + TM - 1) / TM;

    char* ws = (char*)d_ws;
    size_t off_seg = 0;
    size_t off_fs  = (((size_t)(S + 1) * 4) + 255) & ~(size_t)255;
    size_t off_w   = (off_fs + (size_t)NT * 4 + 255) & ~(size_t)255;
    size_t off_pc  = (off_w + (size_t)HID * HID * 2 + 255) & ~(size_t)255;

    int*   seg    = (int*)  (ws + off_seg);
    int*   fsg    = (int*)  (ws + off_fs);
    short* whi    = (short*)(ws + off_w);
    float* pieces = (float*)(ws + off_pc);
    float* z      = (float*)d_out;

    const int blocksB = ((N + 1) + 255) / 256;
    seg_start_kernel<<<blocksB, 256, 0, stream>>>(ow, seg, fsg, N, S);

    prep_w_frag<<<8, 256, 0, stream>>>(W, whi);

    fused_kernel<<<NT, 256, 0, stream>>>(X, whi, bp, wsc, seg, fsg,
                                         pieces, N, S);

    fixup_kernel<<<S, 64, 0, stream>>>(pieces, seg, z);
}